// Round 9
// baseline (184.923 us; speedup 1.0000x reference)
//
#include <hip/hip_runtime.h>

// Perceptual color difference (CIELAB, lightness_weight = 0).
// Inputs: img1, img2 : (B=32, C=3, H=512, W=512) float32, NCHW.
// Output: per-batch mean over HxW of sqrt(da^2 + db^2), 32 floats.
//
// Round 9: round-5 math and streaming structure (absmax 0.0, 38.8 us) with
// the second kernel fused away: deterministic last-block reduction. Each
// block writes its float partial, __threadfence(), then atomicAdd on an int
// counter; the block that observes count==BPB-1 reduces all 128 partials in
// a FIXED order (bitwise deterministic - the atomic only elects the reducer)
// and writes out[b]. Counters are zeroed each call via hipMemsetAsync.
// Rationale: cd_partial streams 201 MB at ~6.3 TB/s = m13's measured
// achievable ceiling (98 MB HBM + ~103 MB L3 through the common L2-miss
// path); the only remaining slack was the cd_final launch + drain overhead.

typedef float v2f __attribute__((ext_vector_type(2)));
typedef float v4f __attribute__((ext_vector_type(4)));

#define HW (512 * 512)
#define NB 32
#define BPB 128                  // blocks per batch
#define THREADS 256
#define STRIDE (BPB * THREADS)   // 32768 float4; nvec = 65536 = 2*STRIDE

__device__ __forceinline__ v2f v2exp2(v2f x) {
    v2f r;
    r.x = __builtin_amdgcn_exp2f(x.x);
    r.y = __builtin_amdgcn_exp2f(x.y);
    return r;
}
__device__ __forceinline__ v2f v2log2(v2f x) {
    v2f r;
    r.x = __builtin_amdgcn_logf(x.x);
    r.y = __builtin_amdgcn_logf(x.y);
    return r;
}

__device__ __forceinline__ v2f srgb2(v2f c) {
    v2f p = v2exp2(v2log2(c + 0.055f) * 2.4f);
    v2f lo = c * 0.08801236f;
    v2f r;
    r.x = (c.x <= 0.04045f) ? lo.x : p.x;
    r.y = (c.y <= 0.04045f) ? lo.y : p.y;
    return r;
}

__device__ __forceinline__ v2f labf2(v2f x, float A, float B, float thr) {
    v2f g = v2exp2(v2log2(x) * (1.0f / 3.0f));
    v2f lo = x * A + B;
    v2f r;
    r.x = (x.x > thr) ? g.x : lo.x;
    r.y = (x.y > thr) ? g.y : lo.y;
    return r;
}

__device__ __forceinline__ void pipe(v2f r, v2f g, v2f u, v2f& apk, v2f& bpk) {
    v2f lr = srgb2(r), lg = srgb2(g), lb = srgb2(u);
    v2f x = lr * 0.3627198f + lg * 0.3144573f + lb * 0.1586792f;
    v2f y = lr * 0.1870275f + lg * 0.6289146f + lb * 0.0634717f;
    v2f z = lr * 0.0170025f + lg * 0.1048191f + lb * 0.8357104f;
    v2f sx = labf2(x, 8.0551810f, 0.13561340f, 0.008417790f);
    v2f sy = labf2(y, 7.7870370f, 0.13793103f, 0.008856452f);
    v2f sz = labf2(z, 7.3575050f, 0.14189940f, 0.009643159f);
    apk = sx * 508.54415f - sy * 500.0f;
    bpk = sy * 200.0f - sz * 194.40678f;
}

__global__ __launch_bounds__(THREADS) void cd_fused(
    const float* __restrict__ img1, const float* __restrict__ img2,
    float* __restrict__ ws, int* __restrict__ cnt, float* __restrict__ out) {
    const int b = blockIdx.y;
    const size_t base = (size_t)b * 3 * HW;
    const v4f* __restrict__ p1 = (const v4f*)(img1 + base);
    const v4f* __restrict__ p2 = (const v4f*)(img2 + base);
    const int coff = HW / 4;

    float sum = 0.0f;
    const int i0 = blockIdx.x * THREADS + threadIdx.x;

#pragma unroll
    for (int chunk = 0; chunk < 2; ++chunk) {
        const int i = i0 + chunk * STRIDE;
        v4f r1 = p1[i], g1 = p1[i + coff], u1 = p1[i + 2 * coff];
        v4f r2 = p2[i], g2 = p2[i + coff], u2 = p2[i + 2 * coff];
#pragma unroll
        for (int h = 0; h < 2; ++h) {
            v2f R1 = h ? __builtin_shufflevector(r1, r1, 2, 3) : __builtin_shufflevector(r1, r1, 0, 1);
            v2f G1 = h ? __builtin_shufflevector(g1, g1, 2, 3) : __builtin_shufflevector(g1, g1, 0, 1);
            v2f U1 = h ? __builtin_shufflevector(u1, u1, 2, 3) : __builtin_shufflevector(u1, u1, 0, 1);
            v2f R2 = h ? __builtin_shufflevector(r2, r2, 2, 3) : __builtin_shufflevector(r2, r2, 0, 1);
            v2f G2 = h ? __builtin_shufflevector(g2, g2, 2, 3) : __builtin_shufflevector(g2, g2, 0, 1);
            v2f U2 = h ? __builtin_shufflevector(u2, u2, 2, 3) : __builtin_shufflevector(u2, u2, 0, 1);
            v2f a1, b1, a2, b2;
            pipe(R1, G1, U1, a1, b1);
            pipe(R2, G2, U2, a2, b2);
            v2f da = a1 - a2;
            v2f db = b1 - b2;
            v2f e = da * da + db * db;
            sum += __builtin_amdgcn_sqrtf(e.x) + __builtin_amdgcn_sqrtf(e.y);
        }
    }

    // ---- phase 1: block partial (wave64 shfl + LDS) ----
#pragma unroll
    for (int off = 32; off > 0; off >>= 1) sum += __shfl_down(sum, off);

    __shared__ float ssum[THREADS / 64];
    __shared__ int amLast;
    const int lane = threadIdx.x & 63;
    const int wid = threadIdx.x >> 6;
    if (lane == 0) ssum[wid] = sum;
    __syncthreads();
    if (threadIdx.x == 0) {
        float s = 0.0f;
#pragma unroll
        for (int w = 0; w < THREADS / 64; ++w) s += ssum[w];
        ws[(size_t)b * BPB + blockIdx.x] = s;
        __threadfence();                       // release partial (device scope)
        int c = atomicAdd(&cnt[b], 1);         // int atomic: elects reducer only
        amLast = (c == BPB - 1) ? 1 : 0;
    }
    __syncthreads();

    // ---- phase 2: elected last block reduces all partials, fixed order ----
    if (amLast) {
        __threadfence();                       // acquire other blocks' partials
        float v = (threadIdx.x < BPB) ? ws[(size_t)b * BPB + threadIdx.x] : 0.0f;
#pragma unroll
        for (int off = 32; off > 0; off >>= 1) v += __shfl_down(v, off);
        if (lane == 0) ssum[wid] = v;
        __syncthreads();
        if (threadIdx.x == 0) {
            float t = 0.0f;
#pragma unroll
            for (int w = 0; w < THREADS / 64; ++w) t += ssum[w];
            out[b] = t * (1.0f / (float)HW);
        }
    }
}

extern "C" void kernel_launch(void* const* d_in, const int* in_sizes, int n_in,
                              void* d_out, int out_size, void* d_ws, size_t ws_size,
                              hipStream_t stream) {
    const float* img1 = (const float*)d_in[0];
    const float* img2 = (const float*)d_in[1];
    float* out = (float*)d_out;
    float* ws = (float*)d_ws;                         // NB*BPB floats = 16 KB
    int* cnt = (int*)((char*)d_ws + NB * BPB * 4);    // NB ints = 128 B

    hipMemsetAsync(cnt, 0, NB * sizeof(int), stream); // graph-capturable

    dim3 grid(BPB, NB);
    cd_fused<<<grid, THREADS, 0, stream>>>(img1, img2, ws, cnt, out);
}

// Round 10
// 69.131 us; speedup vs baseline: 2.6750x; 2.6750x over previous
//
#include <hip/hip_runtime.h>

// Perceptual color difference (CIELAB, lightness_weight = 0).
// Inputs: img1, img2 : (B=32, C=3, H=512, W=512) float32, NCHW.
// Output: per-batch mean over HxW of sqrt(da^2 + db^2), 32 floats.
//
// Round 10: round-5 math/streaming (absmax 0.0) + FENCE-FREE fused reduction.
// Round 9 proved __threadfence() (device-scope, per-XCD L2 writeback) costs
// ~60 us across 4096 blocks. Here: per-batch int64 fixed-point accumulator
// (partial * 2^24; integer adds are order-independent -> bitwise
// deterministic), ordered against the election counter by a DATA DEPENDENCY
// on the acc atomic's return value (RMW result arrives only after it
// executed at the coherence point -> no fence). Winner reads total via RMW.

typedef float v2f __attribute__((ext_vector_type(2)));
typedef float v4f __attribute__((ext_vector_type(4)));

#define HW (512 * 512)
#define NB 32
#define BPB 128                  // blocks per batch
#define THREADS 256
#define STRIDE (BPB * THREADS)   // 32768 float4; nvec = 65536 = 2*STRIDE
#define FXSCALE 16777216.0       // 2^24

__device__ __forceinline__ v2f v2exp2(v2f x) {
    v2f r;
    r.x = __builtin_amdgcn_exp2f(x.x);
    r.y = __builtin_amdgcn_exp2f(x.y);
    return r;
}
__device__ __forceinline__ v2f v2log2(v2f x) {
    v2f r;
    r.x = __builtin_amdgcn_logf(x.x);
    r.y = __builtin_amdgcn_logf(x.y);
    return r;
}

__device__ __forceinline__ v2f srgb2(v2f c) {
    v2f p = v2exp2(v2log2(c + 0.055f) * 2.4f);
    v2f lo = c * 0.08801236f;
    v2f r;
    r.x = (c.x <= 0.04045f) ? lo.x : p.x;
    r.y = (c.y <= 0.04045f) ? lo.y : p.y;
    return r;
}

__device__ __forceinline__ v2f labf2(v2f x, float A, float B, float thr) {
    v2f g = v2exp2(v2log2(x) * (1.0f / 3.0f));
    v2f lo = x * A + B;
    v2f r;
    r.x = (x.x > thr) ? g.x : lo.x;
    r.y = (x.y > thr) ? g.y : lo.y;
    return r;
}

__device__ __forceinline__ void pipe(v2f r, v2f g, v2f u, v2f& apk, v2f& bpk) {
    v2f lr = srgb2(r), lg = srgb2(g), lb = srgb2(u);
    v2f x = lr * 0.3627198f + lg * 0.3144573f + lb * 0.1586792f;
    v2f y = lr * 0.1870275f + lg * 0.6289146f + lb * 0.0634717f;
    v2f z = lr * 0.0170025f + lg * 0.1048191f + lb * 0.8357104f;
    v2f sx = labf2(x, 8.0551810f, 0.13561340f, 0.008417790f);
    v2f sy = labf2(y, 7.7870370f, 0.13793103f, 0.008856452f);
    v2f sz = labf2(z, 7.3575050f, 0.14189940f, 0.009643159f);
    apk = sx * 508.54415f - sy * 500.0f;
    bpk = sy * 200.0f - sz * 194.40678f;
}

__global__ __launch_bounds__(THREADS) void cd_fused(
    const float* __restrict__ img1, const float* __restrict__ img2,
    unsigned long long* __restrict__ acc, int* __restrict__ cnt,
    float* __restrict__ out) {
    const int b = blockIdx.y;
    const size_t base = (size_t)b * 3 * HW;
    const v4f* __restrict__ p1 = (const v4f*)(img1 + base);
    const v4f* __restrict__ p2 = (const v4f*)(img2 + base);
    const int coff = HW / 4;

    float sum = 0.0f;
    const int i0 = blockIdx.x * THREADS + threadIdx.x;

#pragma unroll
    for (int chunk = 0; chunk < 2; ++chunk) {
        const int i = i0 + chunk * STRIDE;
        v4f r1 = p1[i], g1 = p1[i + coff], u1 = p1[i + 2 * coff];
        v4f r2 = p2[i], g2 = p2[i + coff], u2 = p2[i + 2 * coff];
#pragma unroll
        for (int h = 0; h < 2; ++h) {
            v2f R1 = h ? __builtin_shufflevector(r1, r1, 2, 3) : __builtin_shufflevector(r1, r1, 0, 1);
            v2f G1 = h ? __builtin_shufflevector(g1, g1, 2, 3) : __builtin_shufflevector(g1, g1, 0, 1);
            v2f U1 = h ? __builtin_shufflevector(u1, u1, 2, 3) : __builtin_shufflevector(u1, u1, 0, 1);
            v2f R2 = h ? __builtin_shufflevector(r2, r2, 2, 3) : __builtin_shufflevector(r2, r2, 0, 1);
            v2f G2 = h ? __builtin_shufflevector(g2, g2, 2, 3) : __builtin_shufflevector(g2, g2, 0, 1);
            v2f U2 = h ? __builtin_shufflevector(u2, u2, 2, 3) : __builtin_shufflevector(u2, u2, 0, 1);
            v2f a1, b1, a2, b2;
            pipe(R1, G1, U1, a1, b1);
            pipe(R2, G2, U2, a2, b2);
            v2f da = a1 - a2;
            v2f db = b1 - b2;
            v2f e = da * da + db * db;
            sum += __builtin_amdgcn_sqrtf(e.x) + __builtin_amdgcn_sqrtf(e.y);
        }
    }

    // ---- block partial (wave64 shfl + LDS), fixed order ----
#pragma unroll
    for (int off = 32; off > 0; off >>= 1) sum += __shfl_down(sum, off);

    __shared__ float ssum[THREADS / 64];
    const int lane = threadIdx.x & 63;
    const int wid = threadIdx.x >> 6;
    if (lane == 0) ssum[wid] = sum;
    __syncthreads();

    if (threadIdx.x == 0) {
        float s = 0.0f;
#pragma unroll
        for (int w = 0; w < THREADS / 64; ++w) s += ssum[w];

        // int64 fixed-point accumulate: order-independent => deterministic.
        unsigned long long q =
            (unsigned long long)(long long)((double)s * FXSCALE);
        unsigned long long old = atomicAdd(&acc[b], q);
        // Data-dependent election increment: (old >> 63) == 0 always (sums
        // are positive, < 2^63), but the compiler/HW must wait for the acc
        // RMW to return before issuing the counter RMW -> ordering, no fence.
        int c = atomicAdd(&cnt[b], 1 + (int)(old >> 63));
        if (c == BPB - 1) {
            // all 127 other acc-RMWs completed before their cnt-RMWs, which
            // precede ours: an RMW read here sees the full total.
            unsigned long long total = atomicAdd(&acc[b], 0ULL);
            out[b] = (float)((double)(long long)total *
                             (1.0 / (FXSCALE * (double)HW)));
        }
    }
}

extern "C" void kernel_launch(void* const* d_in, const int* in_sizes, int n_in,
                              void* d_out, int out_size, void* d_ws, size_t ws_size,
                              hipStream_t stream) {
    const float* img1 = (const float*)d_in[0];
    const float* img2 = (const float*)d_in[1];
    float* out = (float*)d_out;
    unsigned long long* acc = (unsigned long long*)d_ws;   // NB ull = 256 B
    int* cnt = (int*)((char*)d_ws + NB * sizeof(unsigned long long)); // 128 B

    // zero accumulators + counters (384 B, graph-capturable)
    hipMemsetAsync(d_ws, 0, NB * (sizeof(unsigned long long) + sizeof(int)),
                   stream);

    dim3 grid(BPB, NB);
    cd_fused<<<grid, THREADS, 0, stream>>>(img1, img2, acc, cnt, out);
}

// Round 11
// 38.981 us; speedup vs baseline: 4.7439x; 1.7735x over previous
//
#include <hip/hip_runtime.h>

// Perceptual color difference (CIELAB, lightness_weight = 0).
// Inputs: img1, img2 : (B=32, C=3, H=512, W=512) float32, NCHW.
// Output: per-batch mean over HxW of sqrt(da^2 + db^2), 32 floats.
//
// FINAL (revert to round 5, measured 38.8 us, absmax 0.0):
//  - lightness_weight=0 => L never computed; only a = 500(fx-fy),
//    b = 200(fy-fz).
//  - Gamma scale 1.055^-2.4 folded into the RGB->XYZ matrix; white point
//    folded into the post-cbrt linear combination (derivation below).
//  - Native-instruction transcendentals (v_log_f32 / v_exp_f32 / v_sqrt_f32
//    via __builtin_amdgcn_*): harness compiles without -ffast-math, so
//    libm exp2f/log2f are multi-instruction OCML calls (58.4 -> 38.8 us).
//  - Two-kernel deterministic reduction. Fused single-kernel variants were
//    tried and REGRESSED on this 8-XCD part:
//      __threadfence last-block pattern: 184.9 us (device-scope fence =
//        per-XCD L2 writeback, x8192);
//      fence-free int64-fixpoint atomic protocol: 69.1 us (dependent
//        device-scope RMW chains + 32-line thundering herd at retirement).
//  - Stream delivers ~5.9 TB/s ~ 93% of the measured 6.29 TB/s achievable
//    ceiling (98 MB HBM + ~103 MB L3 through the same fabric path); bytes
//    (201 MB f32, read-once) are irreducible; compute fully hidden
//    (VALUBusy ~30%). This is the practical roofline for this op.
//
// Constant derivation:
//  K   = 1.055^-2.4 = 0.87941365  (folded: M' = K*M, so gamma branch is
//        (c+0.055)^2.4 with no divide)
//  CS1 = 1/(12.92*K) = 0.08801236 (linear-branch scale, pre-matrix)
//  cx  = 0.95047^-1/3 = 1.0170883 ; cz = 1.08883^-1/3 = 0.9720339
//  fx = cx*cbrt(x), etc.; a = 500*(fx-fy) = 508.54415*sx - 500*sy
//  b = 200*(fy-fz) = 200*sy - 194.40678*sz  (s* = cbrt of folded xyz)
//  linear lab branch: A* = 7.787037/(w* * c*), B* = (4/29)/c*
//  thresholds: x > (6/29)^3 * w*

typedef float v2f __attribute__((ext_vector_type(2)));
typedef float v4f __attribute__((ext_vector_type(4)));

#define HW (512 * 512)
#define NB 32
#define BPB 128                  // blocks per batch
#define THREADS 256
#define STRIDE (BPB * THREADS)   // 32768 float4; nvec = 65536 = 2*STRIDE

__device__ __forceinline__ v2f v2exp2(v2f x) {
    v2f r;
    r.x = __builtin_amdgcn_exp2f(x.x);
    r.y = __builtin_amdgcn_exp2f(x.y);
    return r;
}
__device__ __forceinline__ v2f v2log2(v2f x) {
    v2f r;
    r.x = __builtin_amdgcn_logf(x.x);
    r.y = __builtin_amdgcn_logf(x.y);
    return r;
}

__device__ __forceinline__ v2f srgb2(v2f c) {
    v2f p = v2exp2(v2log2(c + 0.055f) * 2.4f);
    v2f lo = c * 0.08801236f;
    v2f r;
    r.x = (c.x <= 0.04045f) ? lo.x : p.x;
    r.y = (c.y <= 0.04045f) ? lo.y : p.y;
    return r;
}

__device__ __forceinline__ v2f labf2(v2f x, float A, float B, float thr) {
    v2f g = v2exp2(v2log2(x) * (1.0f / 3.0f));
    v2f lo = x * A + B;
    v2f r;
    r.x = (x.x > thr) ? g.x : lo.x;
    r.y = (x.y > thr) ? g.y : lo.y;
    return r;
}

__device__ __forceinline__ void pipe(v2f r, v2f g, v2f u, v2f& apk, v2f& bpk) {
    v2f lr = srgb2(r), lg = srgb2(g), lb = srgb2(u);
    v2f x = lr * 0.3627198f + lg * 0.3144573f + lb * 0.1586792f;
    v2f y = lr * 0.1870275f + lg * 0.6289146f + lb * 0.0634717f;
    v2f z = lr * 0.0170025f + lg * 0.1048191f + lb * 0.8357104f;
    v2f sx = labf2(x, 8.0551810f, 0.13561340f, 0.008417790f);
    v2f sy = labf2(y, 7.7870370f, 0.13793103f, 0.008856452f);
    v2f sz = labf2(z, 7.3575050f, 0.14189940f, 0.009643159f);
    apk = sx * 508.54415f - sy * 500.0f;
    bpk = sy * 200.0f - sz * 194.40678f;
}

__global__ __launch_bounds__(THREADS) void cd_partial(
    const float* __restrict__ img1, const float* __restrict__ img2,
    float* __restrict__ ws) {
    const int b = blockIdx.y;
    const size_t base = (size_t)b * 3 * HW;
    const v4f* __restrict__ p1 = (const v4f*)(img1 + base);
    const v4f* __restrict__ p2 = (const v4f*)(img2 + base);
    const int coff = HW / 4;

    float sum = 0.0f;
    const int i0 = blockIdx.x * THREADS + threadIdx.x;

#pragma unroll
    for (int chunk = 0; chunk < 2; ++chunk) {
        const int i = i0 + chunk * STRIDE;
        v4f r1 = p1[i], g1 = p1[i + coff], u1 = p1[i + 2 * coff];
        v4f r2 = p2[i], g2 = p2[i + coff], u2 = p2[i + 2 * coff];
#pragma unroll
        for (int h = 0; h < 2; ++h) {
            v2f R1 = h ? __builtin_shufflevector(r1, r1, 2, 3) : __builtin_shufflevector(r1, r1, 0, 1);
            v2f G1 = h ? __builtin_shufflevector(g1, g1, 2, 3) : __builtin_shufflevector(g1, g1, 0, 1);
            v2f U1 = h ? __builtin_shufflevector(u1, u1, 2, 3) : __builtin_shufflevector(u1, u1, 0, 1);
            v2f R2 = h ? __builtin_shufflevector(r2, r2, 2, 3) : __builtin_shufflevector(r2, r2, 0, 1);
            v2f G2 = h ? __builtin_shufflevector(g2, g2, 2, 3) : __builtin_shufflevector(g2, g2, 0, 1);
            v2f U2 = h ? __builtin_shufflevector(u2, u2, 2, 3) : __builtin_shufflevector(u2, u2, 0, 1);
            v2f a1, b1, a2, b2;
            pipe(R1, G1, U1, a1, b1);
            pipe(R2, G2, U2, a2, b2);
            v2f da = a1 - a2;
            v2f db = b1 - b2;
            v2f e = da * da + db * db;
            sum += __builtin_amdgcn_sqrtf(e.x) + __builtin_amdgcn_sqrtf(e.y);
        }
    }

    // wave64 reduce
#pragma unroll
    for (int off = 32; off > 0; off >>= 1) sum += __shfl_down(sum, off);

    __shared__ float ssum[THREADS / 64];
    const int lane = threadIdx.x & 63;
    const int wid = threadIdx.x >> 6;
    if (lane == 0) ssum[wid] = sum;
    __syncthreads();
    if (threadIdx.x == 0) {
        float s = 0.0f;
#pragma unroll
        for (int w = 0; w < THREADS / 64; ++w) s += ssum[w];
        ws[(size_t)b * BPB + blockIdx.x] = s;
    }
}

// Stage 2: reduce BPB partials per batch, divide by HW.
__global__ __launch_bounds__(64) void cd_final(
    const float* __restrict__ ws, float* __restrict__ out) {
    const int b = blockIdx.x;
    float s = ws[(size_t)b * BPB + threadIdx.x] +
              ws[(size_t)b * BPB + threadIdx.x + 64];
#pragma unroll
    for (int off = 32; off > 0; off >>= 1) s += __shfl_down(s, off);
    if (threadIdx.x == 0) out[b] = s * (1.0f / (float)HW);
}

extern "C" void kernel_launch(void* const* d_in, const int* in_sizes, int n_in,
                              void* d_out, int out_size, void* d_ws, size_t ws_size,
                              hipStream_t stream) {
    const float* img1 = (const float*)d_in[0];
    const float* img2 = (const float*)d_in[1];
    float* out = (float*)d_out;
    float* ws = (float*)d_ws;   // NB * BPB * 4 = 16 KB

    dim3 grid1(BPB, NB);
    cd_partial<<<grid1, THREADS, 0, stream>>>(img1, img2, ws);
    cd_final<<<NB, 64, 0, stream>>>(ws, out);
}